// Round 14
// baseline (578.680 us; speedup 1.0000x reference)
//
#include <hip/hip_runtime.h>
#include <cstdint>
#include <cstddef>

#define T_ 65536

// ---------------- threefry2x32 (bit-exact vs JAX) ----------------
__device__ __forceinline__ void tf2x32(uint32_t k0, uint32_t k1,
                                       uint32_t& x0, uint32_t& x1) {
  const uint32_t ks[3] = {k0, k1, k0 ^ k1 ^ 0x1BD11BDAu};
  const int R[8] = {13, 15, 26, 6, 17, 29, 16, 24};
  x0 += ks[0]; x1 += ks[1];
#pragma unroll
  for (int i = 0; i < 5; ++i) {
#pragma unroll
    for (int j = 0; j < 4; ++j) {
      const int r = R[(i & 1) * 4 + j];
      x0 += x1;
      x1 = (x1 << r) | (x1 >> (32 - r));
      x1 ^= x0;
    }
    x0 += ks[(i + 1) % 3];
    x1 += ks[(i + 2) % 3] + (uint32_t)(i + 1);
  }
}

__device__ __forceinline__ float gumbel_from_bits(uint32_t b) {
  float u = __uint_as_float((b >> 9) | 0x3f800000u) - 1.0f;
  u = fmaxf(u, 1.17549435e-38f);
  return -logf(-logf(u));
}

// ---------------- fused pcp prefix-scan (blocks 0,1) + coef setup (block 2) --
__global__ __launch_bounds__(1024) void pcp_coef_kernel(
    const float* __restrict__ f0, float* __restrict__ pcp,
    const float* __restrict__ da, const float* __restrict__ fa, const float* __restrict__ ra,
    const float* __restrict__ db, const float* __restrict__ fb, const float* __restrict__ rb,
    const float* __restrict__ dc, const float* __restrict__ fc, const float* __restrict__ rc,
    float* __restrict__ cws) {
  __shared__ double sm[1024];
  __shared__ float z[128];
  if (blockIdx.x < 2) {
    const int b = blockIdx.x;
    const int tid = threadIdx.x;
    const float* src = f0 + (size_t)b * T_;
    const int base = tid * 64;
    double loc = 0.0;
#pragma unroll 4
    for (int k = 0; k < 16; ++k) {
      const float4 a = *(const float4*)(src + base + 4 * k);
      loc += 6.283185307179586 * (double)a.x / 48000.0;
      loc += 6.283185307179586 * (double)a.y / 48000.0;
      loc += 6.283185307179586 * (double)a.z / 48000.0;
      loc += 6.283185307179586 * (double)a.w / 48000.0;
    }
    sm[tid] = loc;
    __syncthreads();
    for (int off = 1; off < 1024; off <<= 1) {
      double v = (tid >= off) ? sm[tid - off] : 0.0;
      __syncthreads();
      sm[tid] += v;
      __syncthreads();
    }
    double run = (tid > 0) ? sm[tid - 1] : 0.0;
    float* dst = pcp + (size_t)b * T_;
#pragma unroll 4
    for (int k = 0; k < 16; ++k) {
      const float4 a = *(const float4*)(src + base + 4 * k);
      const double r0 = run + 6.283185307179586 * (double)a.x / 48000.0;
      const double r1 = r0  + 6.283185307179586 * (double)a.y / 48000.0;
      const double r2 = r1  + 6.283185307179586 * (double)a.z / 48000.0;
      const double r3 = r2  + 6.283185307179586 * (double)a.w / 48000.0;
      *(float4*)(dst + base + 4 * k) = make_float4((float)(r0 * 0.5), (float)(r1 * 0.5),
                                                   (float)(r2 * 0.5), (float)(r3 * 0.5));
      run = r3;
    }
  } else {
    uint32_t keys[3][2];
#pragma unroll
    for (int q = 0; q < 3; ++q) {
      uint32_t x0 = 0u, x1 = (uint32_t)q;
      tf2x32(0u, 42u, x0, x1);
      keys[q][0] = x0; keys[q][1] = x1;
    }
    const float* dl[3] = {da, db, dc};
    const float* fg[3] = {fa, fb, fc};
    const float* rf[3] = {ra, rb, rc};
    const int Ls[3] = {85, 85, 8};
    const int md[3] = {40, 40, 32};
    const int i = threadIdx.x;
    for (int r = 0; r < 3; ++r) {
      const int L = Ls[r];
      if (i < 128) z[i] = -3.4e38f;
      __syncthreads();
      if (i < L) {
        uint32_t x0 = 0u, x1 = (uint32_t)i;
        tf2x32(keys[r][0], keys[r][1], x0, x1);
        z[i] = dl[r][i] + gumbel_from_bits(x0 ^ x1);
      }
      __syncthreads();
      if (i == 0) {
        int p = 0; float best = z[0];
        for (int j = 1; j < L; ++j) { float v = z[j]; if (v > best) { best = v; p = j; } }
        const bool lowpass = (r == 2);
        float r0 = rf[r][0], r1 = rf[r][1];
        if (lowpass) { r0 = 1.f / (1.f + expf(-r0)); r1 = 1.f / (1.f + expf(-r1)); }
        else         { r0 = tanhf(r0);               r1 = tanhf(r1); }
        const float k1 = tanhf(r0), k2 = tanhf(r1);
        float a1 = k1 * (1.f - k2);
        const float a2 = fminf(fmaxf(k2, -0.999f), 0.999f);
        const float bnd = 0.999f - fabsf(a2);
        a1 = fminf(fmaxf(a1, -bnd), bnd);
        const float g = powf(1.f / (1.f + expf(-fg[r][0])), 0.45f);
        const int D1 = md[r] + p + 1;
        const int D2 = md[r] + ((p + 1) % L) + 1;
        const float C1 = a1 * g;
        const float C2 = a2 * g;
        float* cw = cws + r * 32;
        const float bin4[5] = {1.f, 4.f, 6.f, 4.f, 1.f};
        const float c1p[5] = {1.f, C1, C1*C1, C1*C1*C1, C1*C1*C1*C1};
        const float c2p[5] = {1.f, C2, C2*C2, C2*C2*C2, C2*C2*C2*C2};
        for (int j = 0; j < 5; ++j) {
          cw[j]     = (float)((4 - j) * D1 + j * D2);
          cw[5 + j] = bin4[j] * c1p[4 - j] * c2p[j];
        }
        const int   fd[9] = {D1, D2, 2*D1, D1+D2, 2*D2, 3*D1, 2*D1+D2, D1+2*D2, 3*D2};
        const float fn[9] = {-C1, -C2, C1*C1, 2.f*C1*C2, C2*C2,
                             -C1*C1*C1, -3.f*C1*C1*C2, -3.f*C1*C2*C2, -C2*C2*C2};
        for (int k = 0; k < 9; ++k) {
          cw[10 + k] = (float)fd[k];
          cw[19 + k] = fn[k];
        }
      }
      __syncthreads();
    }
  }
}

// ---------------- harmonic synth + banks (memory-bound, float4) --------------
__global__ __launch_bounds__(256) void synth_kernel(
    const float* __restrict__ amps,   // (B,512,T)
    const float* __restrict__ fmg,    // (B,1,T)
    const float* __restrict__ cps,    // (B,16,T)
    const float* __restrict__ nba,    // (B,32,T)
    const float* __restrict__ nps,    // (B,2,T)
    const float* __restrict__ npg,    // (B,1,T)
    const float* __restrict__ fng,    // (B,1,T)
    const float* __restrict__ bands,  // (32,T)
    const float* __restrict__ pcp,    // (B,T) ws
    float* __restrict__ bank_a, float* __restrict__ bank_b) {
  const float TPF = 6.283185307179586f;
  const int lane = threadIdx.x & 63;
  const int g    = threadIdx.x >> 6;          // cylinder group 0..3
  const int blk  = blockIdx.x;                // 0..511
  const int b    = blk >> 8;                  // 256 blocks per batch
  const int t    = (blk & 255) * 256 + lane * 4;
  const size_t bt = (size_t)b * T_ + t;

  __shared__ float4 redN[4][64];
  __shared__ float4 redH[4][64];

  const float4 p4 = *(const float4*)(pcp + bt);
  const float4 f4 = *(const float4*)(fmg + bt);

  float4 nse = make_float4(0.f, 0.f, 0.f, 0.f);
#pragma unroll
  for (int j = 0; j < 8; ++j) {
    const int n = g * 8 + j;
    const float4 a = *(const float4*)(nba + ((size_t)b * 32 + n) * T_ + t);
    const float4 w = *(const float4*)(bands + (size_t)n * T_ + t);
    nse.x += a.x * w.x; nse.y += a.y * w.y;
    nse.z += a.z * w.z; nse.w += a.w * w.w;
  }
  redN[g][lane] = nse;

  const int order[8] = {0, 4, 3, 7, 5, 2, 6, 1};
  float4 hp = make_float4(0.f, 0.f, 0.f, 0.f);
#pragma unroll
  for (int cc = 0; cc < 2; ++cc) {
    const int c = 2 * g + cc;
    const float ang = ((float)order[c] / 8.0f) * TPF;
#define SETUP(C_)                                                     \
    float s##C_ = p4.C_ + ang; if (s##C_ >= TPF) s##C_ -= TPF;        \
    float sn##C_, cs##C_;                                             \
    sincosf(TPF * powf(s##C_ / TPF, f4.C_), &sn##C_, &cs##C_);        \
    float sp##C_ = 0.f, sc##C_ = sn##C_;                              \
    const float tc##C_ = 2.f * cs##C_;                                \
    float acc##C_ = 0.f;
    SETUP(x) SETUP(y) SETUP(z) SETUP(w)
#undef SETUP
    const float* ap = amps + ((size_t)b * 512 + (size_t)c * 64) * T_ + t;
#pragma unroll 4
    for (int h = 0; h < 64; ++h) {
      const float4 a = *(const float4*)(ap + (size_t)h * T_);
#define HSTEP(C_) {                                                   \
      acc##C_ += a.C_ * sc##C_;                                       \
      const float nx = tc##C_ * sc##C_ - sp##C_;                      \
      sp##C_ = sc##C_; sc##C_ = nx; }
      HSTEP(x) HSTEP(y) HSTEP(z) HSTEP(w)
#undef HSTEP
    }
    const float4 al = *(const float4*)(cps + ((size_t)b * 16 + c) * T_ + t);
    const float4 be = *(const float4*)(cps + ((size_t)b * 16 + 8 + c) * T_ + t);
#define ENVACC(C_) {                                                  \
      const float env = (1.f - expf(-al.C_ * s##C_)) * expf(-be.C_ * s##C_); \
      hp.C_ += -acc##C_ * env * 10.f; }
    ENVACC(x) ENVACC(y) ENVACC(z) ENVACC(w)
#undef ENVACC
  }
  redH[g][lane] = hp;
  __syncthreads();

  if (g == 0) {
    const float4 nA = redN[0][lane], nB = redN[1][lane],
                 nC = redN[2][lane], nD = redN[3][lane];
    const float4 hA0 = redH[0][lane], hA1 = redH[1][lane],
                 hB0 = redH[2][lane], hB1 = redH[3][lane];
    const float4 g4  = *(const float4*)(npg + bt);
    const float4 fl4 = *(const float4*)(fng + bt);
    const float4 na4 = *(const float4*)(nps + (size_t)b * 2 * T_ + t);
    const float4 nb4 = *(const float4*)(nps + ((size_t)b * 2 + 1) * T_ + t);
    float4 outA, outB;
#define FIN(C_) {                                                     \
    const float nse = nA.C_ + nB.C_ + nC.C_ + nD.C_;                  \
    const float ha = hA0.C_ + hA1.C_;                                 \
    const float hb = hB0.C_ + hB1.C_;                                 \
    float q = p4.C_; if (q >= TPF) q -= TPF;                          \
    const float ne = (1.f - expf(-na4.C_ * q)) * expf(-nb4.C_ * q);   \
    const float com = nse * (ne * g4.C_ + fl4.C_ * 0.3f);             \
    const float K = nse * (g4.C_ + fl4.C_) * 0.7f;                    \
    outA.C_ = ha * (1.f + K) + 4.f * com;                             \
    outB.C_ = hb * (1.f + K) + 4.f * com; }
    FIN(x) FIN(y) FIN(z) FIN(w)
#undef FIN
    *(float4*)(bank_a + bt) = outA;
    *(float4*)(bank_b + bt) = outB;
  }
}

// ---------------- fused feedforward + resonator scan ------------------------
// 4 waves/block. Wave 0: serial delay-quadrupled 5-tap recurrence (identical
// to round 13: 128 samples/iter, prefetched taps, ring bulk-flush). Waves 1-3:
// producers -- compute x''[t] = x[t] + SUM n_k x[t-d_k] for phase ph+1 from
// GLOBAL memory (input arrays fully written by the previous kernel launch)
// into a double-buffered LDS xbuf; one __syncthreads per phase. This deletes
// the prep kernels, their launch gaps, and the scan's global_load_lds staging
// (xv now comes from xbuf). Producer loads are L2/L3 hits overlapped under
// wave0's serial phase on other SIMDs of the CU.
template <bool TWO_IN>
__device__ __forceinline__ void fused_scan(const float* __restrict__ x1,
                                           const float* __restrict__ x2,
                                           float* __restrict__ y,
                                           const float* __restrict__ cf,
                                           float* __restrict__ sm) {
  const int tid = threadIdx.x;
  const int wid = tid >> 6;
  const int o = tid & 63;
  float* ring = sm;            // 1024 floats (wave0 only)
  float* xb   = sm + 1024;     // 2 x 1024 floats (producers -> wave0)

  const int e0 = (int)cf[0], e1 = (int)cf[1], e2 = (int)cf[2],
            e3 = (int)cf[3], e4 = (int)cf[4];
  const float fc0 = cf[5], fc1 = cf[6], fc2 = cf[7], fc3 = cf[8], fc4 = cf[9];
  int   fd[9];
  float fn[9];
#pragma unroll
  for (int k = 0; k < 9; ++k) { fd[k] = (int)cf[10 + k]; fn[k] = cf[19 + k]; }

  // producer body: x'' for samples [base, base+1024) -> xb bank (base>>10)&1
#define PRODUCE(BASE)                                                         \
  {                                                                           \
    const int tid1 = tid - 64;                                                \
    float* dst = xb + (((BASE) >> 10) & 1) * 1024;                            \
    for (int s = tid1; s < 256; s += 192) {                                   \
      const int t0 = (BASE) + 4 * s;                                          \
      float4 xv = *(const float4*)(x1 + t0);                                  \
      if (TWO_IN) { const float4 w = *(const float4*)(x2 + t0);               \
        xv.x += w.x; xv.y += w.y; xv.z += w.z; xv.w += w.w; }                 \
      float c0 = xv.x, c1 = xv.y, c2 = xv.z, c3 = xv.w;                       \
      _Pragma("unroll")                                                       \
      for (int k = 0; k < 9; ++k) {                                           \
        const int d = fd[k]; const float n = fn[k];                           \
        { const int tc = t0 + 0 - d; float u = x1[tc >= 0 ? tc : 0];          \
          if (TWO_IN) u += x2[tc >= 0 ? tc : 0];                              \
          c0 += (tc >= 0) ? n * u : 0.f; }                                    \
        { const int tc = t0 + 1 - d; float u = x1[tc >= 0 ? tc : 0];          \
          if (TWO_IN) u += x2[tc >= 0 ? tc : 0];                              \
          c1 += (tc >= 0) ? n * u : 0.f; }                                    \
        { const int tc = t0 + 2 - d; float u = x1[tc >= 0 ? tc : 0];          \
          if (TWO_IN) u += x2[tc >= 0 ? tc : 0];                              \
          c2 += (tc >= 0) ? n * u : 0.f; }                                    \
        { const int tc = t0 + 3 - d; float u = x1[tc >= 0 ? tc : 0];          \
          if (TWO_IN) u += x2[tc >= 0 ? tc : 0];                              \
          c3 += (tc >= 0) ? n * u : 0.f; }                                    \
      }                                                                       \
      *(float4*)(dst + 4 * s) = make_float4(c0, c1, c2, c3);                  \
    }                                                                         \
  }

  if (wid == 0) {
#pragma unroll
    for (int i = 0; i < 16; ++i) ring[o + i * 64] = 0.f;
  } else {
    PRODUCE(0)                 // phase 0 -> xb bank 0
  }
  __syncthreads();

  // wave0 tap registers: priming reads of the zeroed ring are all 0
  float a0 = 0.f, a1v = 0.f, a2v = 0.f, a3v = 0.f, a4v = 0.f;
  float b0 = 0.f, b1v = 0.f, b2v = 0.f, b3v = 0.f, b4v = 0.f;

  int m = 0;
  for (int ph = 0; ph < 64; ++ph) {
    if (wid == 0) {
      const float* bq = xb + (ph & 1) * 1024;
      float xv0 = bq[o];
      float xv1 = bq[64 + o];
#pragma unroll
      for (int li = 0; li < 8; ++li) {
        const float sA = fmaf(fc0, a0, fc1 * a1v) + fmaf(fc2, a2v, fc3 * a3v);
        const float y0 = xv0 + fmaf(fc4, a4v, sA);
        ring[(m + o) & 1023] = y0;
        const float sB = fmaf(fc0, b0, fc1 * b1v) + fmaf(fc2, b2v, fc3 * b3v);
        const float y1 = xv1 + fmaf(fc4, b4v, sB);
        ring[(m + 64 + o) & 1023] = y1;
        // prefetch taps for iteration m+128 (targets <= m+59: written above
        // or earlier; in-order DS within the wave)
        a0  = ring[(m + 128 + o - e0) & 1023];
        a1v = ring[(m + 128 + o - e1) & 1023];
        a2v = ring[(m + 128 + o - e2) & 1023];
        a3v = ring[(m + 128 + o - e3) & 1023];
        a4v = ring[(m + 128 + o - e4) & 1023];
        b0  = ring[(m + 192 + o - e0) & 1023];
        b1v = ring[(m + 192 + o - e1) & 1023];
        b2v = ring[(m + 192 + o - e2) & 1023];
        b3v = ring[(m + 192 + o - e3) & 1023];
        b4v = ring[(m + 192 + o - e4) & 1023];
        if (li < 7) { xv0 = bq[(li + 1) * 128 + o]; xv1 = bq[(li + 1) * 128 + 64 + o]; }
        m += 128;
      }
      // bulk-flush: ring slot k holds y[ph*1024 + k] exactly (1024-aligned)
#pragma unroll
      for (int j = 0; j < 4; ++j) {
        const float4 v = *(const float4*)(ring + (o << 2) + j * 256);
        *(float4*)(y + ph * 1024 + j * 256 + (o << 2)) = v;
      }
    } else if (ph + 1 < 64) {
      PRODUCE((ph + 1) * 1024)
    }
    __syncthreads();
  }
#undef PRODUCE
}

__global__ __launch_bounds__(256) void res_ab_kernel(
    const float* __restrict__ BA, const float* __restrict__ BB,
    float* __restrict__ RA, float* __restrict__ RB, const float* __restrict__ CW) {
  __shared__ float sm[3072];
  const int r = blockIdx.x >> 1;
  const int b = blockIdx.x & 1;
  fused_scan<false>((r == 0 ? BA : BB) + (size_t)b * T_, nullptr,
                    (r == 0 ? RA : RB) + (size_t)b * T_, CW + r * 32, sm);
}

__global__ __launch_bounds__(256) void res_c_kernel(
    const float* __restrict__ RA, const float* __restrict__ RB,
    float* __restrict__ out, const float* __restrict__ CW) {
  __shared__ float sm[3072];
  const int b = blockIdx.x;
  fused_scan<true>(RA + (size_t)b * T_, RB + (size_t)b * T_,
                   out + (size_t)b * T_, CW + 64, sm);
}

// ---------------- launch ----------------
extern "C" void kernel_launch(void* const* d_in, const int* in_sizes, int n_in,
                              void* d_out, int out_size, void* d_ws, size_t ws_size,
                              hipStream_t stream) {
  const float* f0    = (const float*)d_in[0];
  const float* amps  = (const float*)d_in[1];
  const float* fmg   = (const float*)d_in[2];
  const float* cps   = (const float*)d_in[4];
  const float* nba   = (const float*)d_in[5];
  const float* nps   = (const float*)d_in[6];
  const float* npg   = (const float*)d_in[7];
  const float* fng   = (const float*)d_in[8];
  const float* bands = (const float*)d_in[9];
  const float* da  = (const float*)d_in[10];
  const float* fga = (const float*)d_in[11];
  const float* ra  = (const float*)d_in[12];
  const float* db  = (const float*)d_in[13];
  const float* fgb = (const float*)d_in[14];
  const float* rb  = (const float*)d_in[15];
  const float* dc  = (const float*)d_in[16];
  const float* fgc = (const float*)d_in[17];
  const float* rc  = (const float*)d_in[18];
  float* out = (float*)d_out;
  float* ws  = (float*)d_ws;

  // slots of 131072 floats (B*T):
  float* S0 = ws;              // pcp -> later RA (res_a)   [disjoint from banks]
  float* S1 = ws + 131072;     // bank_a (stays live through res_ab)
  float* S2 = ws + 262144;     // bank_b (stays live through res_ab)
  float* S3 = ws + 393216;     // RB (res_b)
  float* CW = ws + 524288;     // coefficients (96 floats)

  pcp_coef_kernel<<<3, 1024, 0, stream>>>(f0, S0, da, fga, ra, db, fgb, rb,
                                          dc, fgc, rc, CW);
  synth_kernel<<<512, 256, 0, stream>>>(amps, fmg, cps, nba, nps, npg, fng, bands,
                                        S0, S1, S2);
  // fused ff+scan for banks: reads banks S1,S2 (global), RA->S0 (pcp dead), RB->S3
  res_ab_kernel<<<4, 256, 0, stream>>>(S1, S2, S0, S3, CW);
  // fused ff+scan for c: reads RA=S0, RB=S3 (global), writes out
  res_c_kernel<<<2, 256, 0, stream>>>(S0, S3, out, CW);
}

// Round 15
// 253.437 us; speedup vs baseline: 2.2833x; 2.2833x over previous
//
#include <hip/hip_runtime.h>
#include <cstdint>
#include <cstddef>

#define T_ 65536

// ---------------- threefry2x32 (bit-exact vs JAX) ----------------
__device__ __forceinline__ void tf2x32(uint32_t k0, uint32_t k1,
                                       uint32_t& x0, uint32_t& x1) {
  const uint32_t ks[3] = {k0, k1, k0 ^ k1 ^ 0x1BD11BDAu};
  const int R[8] = {13, 15, 26, 6, 17, 29, 16, 24};
  x0 += ks[0]; x1 += ks[1];
#pragma unroll
  for (int i = 0; i < 5; ++i) {
#pragma unroll
    for (int j = 0; j < 4; ++j) {
      const int r = R[(i & 1) * 4 + j];
      x0 += x1;
      x1 = (x1 << r) | (x1 >> (32 - r));
      x1 ^= x0;
    }
    x0 += ks[(i + 1) % 3];
    x1 += ks[(i + 2) % 3] + (uint32_t)(i + 1);
  }
}

__device__ __forceinline__ float gumbel_from_bits(uint32_t b) {
  float u = __uint_as_float((b >> 9) | 0x3f800000u) - 1.0f;
  u = fmaxf(u, 1.17549435e-38f);
  return -logf(-logf(u));
}

// ---------------- fused pcp prefix-scan (blocks 0,1) + coef setup (block 2) --
__global__ __launch_bounds__(1024) void pcp_coef_kernel(
    const float* __restrict__ f0, float* __restrict__ pcp,
    const float* __restrict__ da, const float* __restrict__ fa, const float* __restrict__ ra,
    const float* __restrict__ db, const float* __restrict__ fb, const float* __restrict__ rb,
    const float* __restrict__ dc, const float* __restrict__ fc, const float* __restrict__ rc,
    float* __restrict__ cws) {
  __shared__ double sm[1024];
  __shared__ float z[128];
  if (blockIdx.x < 2) {
    const int b = blockIdx.x;
    const int tid = threadIdx.x;
    const float* src = f0 + (size_t)b * T_;
    const int base = tid * 64;
    double loc = 0.0;
#pragma unroll 4
    for (int k = 0; k < 16; ++k) {
      const float4 a = *(const float4*)(src + base + 4 * k);
      loc += 6.283185307179586 * (double)a.x / 48000.0;
      loc += 6.283185307179586 * (double)a.y / 48000.0;
      loc += 6.283185307179586 * (double)a.z / 48000.0;
      loc += 6.283185307179586 * (double)a.w / 48000.0;
    }
    sm[tid] = loc;
    __syncthreads();
    for (int off = 1; off < 1024; off <<= 1) {
      double v = (tid >= off) ? sm[tid - off] : 0.0;
      __syncthreads();
      sm[tid] += v;
      __syncthreads();
    }
    double run = (tid > 0) ? sm[tid - 1] : 0.0;
    float* dst = pcp + (size_t)b * T_;
#pragma unroll 4
    for (int k = 0; k < 16; ++k) {
      const float4 a = *(const float4*)(src + base + 4 * k);
      const double r0 = run + 6.283185307179586 * (double)a.x / 48000.0;
      const double r1 = r0  + 6.283185307179586 * (double)a.y / 48000.0;
      const double r2 = r1  + 6.283185307179586 * (double)a.z / 48000.0;
      const double r3 = r2  + 6.283185307179586 * (double)a.w / 48000.0;
      *(float4*)(dst + base + 4 * k) = make_float4((float)(r0 * 0.5), (float)(r1 * 0.5),
                                                   (float)(r2 * 0.5), (float)(r3 * 0.5));
      run = r3;
    }
  } else {
    uint32_t keys[3][2];
#pragma unroll
    for (int q = 0; q < 3; ++q) {
      uint32_t x0 = 0u, x1 = (uint32_t)q;
      tf2x32(0u, 42u, x0, x1);
      keys[q][0] = x0; keys[q][1] = x1;
    }
    const float* dl[3] = {da, db, dc};
    const float* fg[3] = {fa, fb, fc};
    const float* rf[3] = {ra, rb, rc};
    const int Ls[3] = {85, 85, 8};
    const int md[3] = {40, 40, 32};
    const int i = threadIdx.x;
    for (int r = 0; r < 3; ++r) {
      const int L = Ls[r];
      if (i < 128) z[i] = -3.4e38f;
      __syncthreads();
      if (i < L) {
        uint32_t x0 = 0u, x1 = (uint32_t)i;
        tf2x32(keys[r][0], keys[r][1], x0, x1);
        z[i] = dl[r][i] + gumbel_from_bits(x0 ^ x1);
      }
      __syncthreads();
      if (i == 0) {
        int p = 0; float best = z[0];
        for (int j = 1; j < L; ++j) { float v = z[j]; if (v > best) { best = v; p = j; } }
        const bool lowpass = (r == 2);
        float r0 = rf[r][0], r1 = rf[r][1];
        if (lowpass) { r0 = 1.f / (1.f + expf(-r0)); r1 = 1.f / (1.f + expf(-r1)); }
        else         { r0 = tanhf(r0);               r1 = tanhf(r1); }
        const float k1 = tanhf(r0), k2 = tanhf(r1);
        float a1 = k1 * (1.f - k2);
        const float a2 = fminf(fmaxf(k2, -0.999f), 0.999f);
        const float bnd = 0.999f - fabsf(a2);
        a1 = fminf(fmaxf(a1, -bnd), bnd);
        const float g = powf(1.f / (1.f + expf(-fg[r][0])), 0.45f);
        const int D1 = md[r] + p + 1;
        const int D2 = md[r] + ((p + 1) % L) + 1;
        const float C1 = a1 * g;
        const float C2 = a2 * g;
        float* cw = cws + r * 32;
        const float bin4[5] = {1.f, 4.f, 6.f, 4.f, 1.f};
        const float c1p[5] = {1.f, C1, C1*C1, C1*C1*C1, C1*C1*C1*C1};
        const float c2p[5] = {1.f, C2, C2*C2, C2*C2*C2, C2*C2*C2*C2};
        for (int j = 0; j < 5; ++j) {
          cw[j]     = (float)((4 - j) * D1 + j * D2);
          cw[5 + j] = bin4[j] * c1p[4 - j] * c2p[j];
        }
        const int   fd[9] = {D1, D2, 2*D1, D1+D2, 2*D2, 3*D1, 2*D1+D2, D1+2*D2, 3*D2};
        const float fn[9] = {-C1, -C2, C1*C1, 2.f*C1*C2, C2*C2,
                             -C1*C1*C1, -3.f*C1*C1*C2, -3.f*C1*C2*C2, -C2*C2*C2};
        for (int k = 0; k < 9; ++k) {
          cw[10 + k] = (float)fd[k];
          cw[19 + k] = fn[k];
        }
      }
      __syncthreads();
    }
  }
}

// ---------------- harmonic synth + banks (memory-bound, float4) --------------
__global__ __launch_bounds__(256) void synth_kernel(
    const float* __restrict__ amps,   // (B,512,T)
    const float* __restrict__ fmg,    // (B,1,T)
    const float* __restrict__ cps,    // (B,16,T)
    const float* __restrict__ nba,    // (B,32,T)
    const float* __restrict__ nps,    // (B,2,T)
    const float* __restrict__ npg,    // (B,1,T)
    const float* __restrict__ fng,    // (B,1,T)
    const float* __restrict__ bands,  // (32,T)
    const float* __restrict__ pcp,    // (B,T) ws
    float* __restrict__ bank_a, float* __restrict__ bank_b) {
  const float TPF = 6.283185307179586f;
  const int lane = threadIdx.x & 63;
  const int g    = threadIdx.x >> 6;          // cylinder group 0..3
  const int blk  = blockIdx.x;                // 0..511
  const int b    = blk >> 8;                  // 256 blocks per batch
  const int t    = (blk & 255) * 256 + lane * 4;
  const size_t bt = (size_t)b * T_ + t;

  __shared__ float4 redN[4][64];
  __shared__ float4 redH[4][64];

  const float4 p4 = *(const float4*)(pcp + bt);
  const float4 f4 = *(const float4*)(fmg + bt);

  float4 nse = make_float4(0.f, 0.f, 0.f, 0.f);
#pragma unroll
  for (int j = 0; j < 8; ++j) {
    const int n = g * 8 + j;
    const float4 a = *(const float4*)(nba + ((size_t)b * 32 + n) * T_ + t);
    const float4 w = *(const float4*)(bands + (size_t)n * T_ + t);
    nse.x += a.x * w.x; nse.y += a.y * w.y;
    nse.z += a.z * w.z; nse.w += a.w * w.w;
  }
  redN[g][lane] = nse;

  const int order[8] = {0, 4, 3, 7, 5, 2, 6, 1};
  float4 hp = make_float4(0.f, 0.f, 0.f, 0.f);
#pragma unroll
  for (int cc = 0; cc < 2; ++cc) {
    const int c = 2 * g + cc;
    const float ang = ((float)order[c] / 8.0f) * TPF;
#define SETUP(C_)                                                     \
    float s##C_ = p4.C_ + ang; if (s##C_ >= TPF) s##C_ -= TPF;        \
    float sn##C_, cs##C_;                                             \
    sincosf(TPF * powf(s##C_ / TPF, f4.C_), &sn##C_, &cs##C_);        \
    float sp##C_ = 0.f, sc##C_ = sn##C_;                              \
    const float tc##C_ = 2.f * cs##C_;                                \
    float acc##C_ = 0.f;
    SETUP(x) SETUP(y) SETUP(z) SETUP(w)
#undef SETUP
    const float* ap = amps + ((size_t)b * 512 + (size_t)c * 64) * T_ + t;
#pragma unroll 4
    for (int h = 0; h < 64; ++h) {
      const float4 a = *(const float4*)(ap + (size_t)h * T_);
#define HSTEP(C_) {                                                   \
      acc##C_ += a.C_ * sc##C_;                                       \
      const float nx = tc##C_ * sc##C_ - sp##C_;                      \
      sp##C_ = sc##C_; sc##C_ = nx; }
      HSTEP(x) HSTEP(y) HSTEP(z) HSTEP(w)
#undef HSTEP
    }
    const float4 al = *(const float4*)(cps + ((size_t)b * 16 + c) * T_ + t);
    const float4 be = *(const float4*)(cps + ((size_t)b * 16 + 8 + c) * T_ + t);
#define ENVACC(C_) {                                                  \
      const float env = (1.f - expf(-al.C_ * s##C_)) * expf(-be.C_ * s##C_); \
      hp.C_ += -acc##C_ * env * 10.f; }
    ENVACC(x) ENVACC(y) ENVACC(z) ENVACC(w)
#undef ENVACC
  }
  redH[g][lane] = hp;
  __syncthreads();

  if (g == 0) {
    const float4 nA = redN[0][lane], nB = redN[1][lane],
                 nC = redN[2][lane], nD = redN[3][lane];
    const float4 hA0 = redH[0][lane], hA1 = redH[1][lane],
                 hB0 = redH[2][lane], hB1 = redH[3][lane];
    const float4 g4  = *(const float4*)(npg + bt);
    const float4 fl4 = *(const float4*)(fng + bt);
    const float4 na4 = *(const float4*)(nps + (size_t)b * 2 * T_ + t);
    const float4 nb4 = *(const float4*)(nps + ((size_t)b * 2 + 1) * T_ + t);
    float4 outA, outB;
#define FIN(C_) {                                                     \
    const float nse = nA.C_ + nB.C_ + nC.C_ + nD.C_;                  \
    const float ha = hA0.C_ + hA1.C_;                                 \
    const float hb = hB0.C_ + hB1.C_;                                 \
    float q = p4.C_; if (q >= TPF) q -= TPF;                          \
    const float ne = (1.f - expf(-na4.C_ * q)) * expf(-nb4.C_ * q);   \
    const float com = nse * (ne * g4.C_ + fl4.C_ * 0.3f);             \
    const float K = nse * (g4.C_ + fl4.C_) * 0.7f;                    \
    outA.C_ = ha * (1.f + K) + 4.f * com;                             \
    outB.C_ = hb * (1.f + K) + 4.f * com; }
    FIN(x) FIN(y) FIN(z) FIN(w)
#undef FIN
    *(float4*)(bank_a + bt) = outA;
    *(float4*)(bank_b + bt) = outB;
  }
}

// ---------------- feedforward prep: x'' = x + SUM n_k x[t-d_k] (float4) -----
__global__ __launch_bounds__(256) void prep_ab_kernel(
    const float* __restrict__ BA, const float* __restrict__ BB,
    const float* __restrict__ CW, float* __restrict__ XA, float* __restrict__ XB) {
  const int idx = blockIdx.x * 256 + threadIdx.x;   // 0..65535
  const int t0 = (idx & 16383) * 4;
  const int s = idx >> 14;                           // 0..3
  const int r = s >> 1, b = s & 1;
  const float* xin = (r == 0 ? BA : BB) + (size_t)b * T_;
  float* xout = (r == 0 ? XA : XB) + (size_t)b * T_;
  const float* cw = CW + r * 32;
  const float4 xv = *(const float4*)(xin + t0);
  float c0 = xv.x, c1 = xv.y, c2 = xv.z, c3 = xv.w;
#pragma unroll
  for (int k = 0; k < 9; ++k) {
    const int d = (int)cw[10 + k];
    const float n = cw[19 + k];
#define TAP(J, CJ) { const int tc = t0 + (J) - d;                     \
      const float u = xin[tc >= 0 ? tc : 0];                          \
      CJ += (tc >= 0) ? n * u : 0.f; }
    TAP(0, c0) TAP(1, c1) TAP(2, c2) TAP(3, c3)
#undef TAP
  }
  *(float4*)(xout + t0) = make_float4(c0, c1, c2, c3);
}

__global__ __launch_bounds__(256) void prep_c_kernel(
    const float* __restrict__ RA, const float* __restrict__ RB,
    const float* __restrict__ CW, float* __restrict__ XC) {
  const int idx = blockIdx.x * 256 + threadIdx.x;   // 0..32767
  const int t0 = (idx & 16383) * 4;
  const int b = idx >> 14;
  const float* ya = RA + (size_t)b * T_;
  const float* yb = RB + (size_t)b * T_;
  const float* cw = CW + 64;
  const float4 va = *(const float4*)(ya + t0);
  const float4 vb = *(const float4*)(yb + t0);
  float c0 = va.x + vb.x, c1 = va.y + vb.y, c2 = va.z + vb.z, c3 = va.w + vb.w;
#pragma unroll
  for (int k = 0; k < 9; ++k) {
    const int d = (int)cw[10 + k];
    const float n = cw[19 + k];
#define TAP(J, CJ) { const int tc = t0 + (J) - d;                     \
      const int ti = tc >= 0 ? tc : 0;                                \
      const float u = ya[ti] + yb[ti];                                \
      CJ += (tc >= 0) ? n * u : 0.f; }
    TAP(0, c0) TAP(1, c1) TAP(2, c2) TAP(3, c3)
#undef TAP
  }
  *(float4*)(XC + (size_t)b * T_ + t0) = make_float4(c0, c1, c2, c3);
}

// ---------------- resonator scan: delay-quadrupled 5-tap recurrence ----------
// Round-13 structure (proven 248.7 us): 128 samples/iteration (valid: all
// E >= 132 > 128+4), 512 iterations, per-step global stores replaced by a
// once-per-phase bulk ring-flush, triple-buffered global_load_lds staging,
// counted s_waitcnt vmcnt(8) per phase.
__device__ __forceinline__ void gld16(const float* g, float* l) {
  __builtin_amdgcn_global_load_lds((const __attribute__((address_space(1))) void*)g,
                                   (__attribute__((address_space(3))) void*)l, 16, 0, 0);
}

__device__ __forceinline__ void poly_scan(const float* __restrict__ x,
                                          float* __restrict__ y,
                                          const float* __restrict__ cf,
                                          float* __restrict__ sm) {
  const int o = threadIdx.x & 63;
  const int e0 = (int)cf[0], e1 = (int)cf[1], e2 = (int)cf[2],
            e3 = (int)cf[3], e4 = (int)cf[4];
  const float fc0 = cf[5], fc1 = cf[6], fc2 = cf[7], fc3 = cf[8], fc4 = cf[9];
  float* ring = sm;          // 1024 floats
  float* st   = sm + 1024;   // 3 x 1024 floats staging

#pragma unroll
  for (int i = 0; i < 16; ++i) ring[o + i * 64] = 0.f;

#pragma unroll
  for (int seg = 0; seg < 2; ++seg) {
    const float* g = x + seg * 1024 + (o << 2);
    float* l = st + seg * 1024;
    gld16(g, l); gld16(g + 256, l + 256);
    gld16(g + 512, l + 512); gld16(g + 768, l + 768);
  }
  asm volatile("s_waitcnt vmcnt(4)" ::: "memory");   // segment 0 resident
  __builtin_amdgcn_sched_barrier(0);

  float a0 = ring[(o - e0) & 1023];
  float a1v = ring[(o - e1) & 1023];
  float a2v = ring[(o - e2) & 1023];
  float a3v = ring[(o - e3) & 1023];
  float a4v = ring[(o - e4) & 1023];
  float b0 = ring[(o + 64 - e0) & 1023];
  float b1v = ring[(o + 64 - e1) & 1023];
  float b2v = ring[(o + 64 - e2) & 1023];
  float b3v = ring[(o + 64 - e3) & 1023];
  float b4v = ring[(o + 64 - e4) & 1023];

  int m = 0;   // sample base of current 128-sample iteration
  for (int ph = 0; ph < 64; ++ph) {
    if (ph < 62) {
      const int seg = ph + 2;
      const float* g = x + seg * 1024 + (o << 2);
      float* l = st + (seg % 3) * 1024;
      gld16(g, l); gld16(g + 256, l + 256);
      gld16(g + 512, l + 512); gld16(g + 768, l + 768);
    }
    const float* bq = st + (ph % 3) * 1024;
    float xv0 = bq[o];
    float xv1 = bq[64 + o];
#pragma unroll
    for (int li = 0; li < 8; ++li) {
      const float sA = fmaf(fc0, a0, fc1 * a1v) + fmaf(fc2, a2v, fc3 * a3v);
      const float y0 = xv0 + fmaf(fc4, a4v, sA);
      ring[(m + o) & 1023] = y0;
      const float sB = fmaf(fc0, b0, fc1 * b1v) + fmaf(fc2, b2v, fc3 * b3v);
      const float y1 = xv1 + fmaf(fc4, b4v, sB);
      ring[(m + 64 + o) & 1023] = y1;
      a0  = ring[(m + 128 + o - e0) & 1023];
      a1v = ring[(m + 128 + o - e1) & 1023];
      a2v = ring[(m + 128 + o - e2) & 1023];
      a3v = ring[(m + 128 + o - e3) & 1023];
      a4v = ring[(m + 128 + o - e4) & 1023];
      b0  = ring[(m + 192 + o - e0) & 1023];
      b1v = ring[(m + 192 + o - e1) & 1023];
      b2v = ring[(m + 192 + o - e2) & 1023];
      b3v = ring[(m + 192 + o - e3) & 1023];
      b4v = ring[(m + 192 + o - e4) & 1023];
      if (li < 7) { xv0 = bq[(li + 1) * 128 + o]; xv1 = bq[(li + 1) * 128 + 64 + o]; }
      m += 128;
    }
#pragma unroll
    for (int j = 0; j < 4; ++j) {
      const float4 v = *(const float4*)(ring + (o << 2) + j * 256);
      *(float4*)(y + ph * 1024 + j * 256 + (o << 2)) = v;
    }
    asm volatile("s_waitcnt vmcnt(8)" ::: "memory");
    __builtin_amdgcn_sched_barrier(0);
  }
}

__global__ __launch_bounds__(64) void res_ab_kernel(
    const float* __restrict__ XA, const float* __restrict__ XB,
    float* __restrict__ RA, float* __restrict__ RB, const float* __restrict__ CW) {
  __shared__ float sm[4096];
  const int r = blockIdx.x >> 1;
  const int b = blockIdx.x & 1;
  poly_scan((r == 0 ? XA : XB) + (size_t)b * T_,
            (r == 0 ? RA : RB) + (size_t)b * T_, CW + r * 32, sm);
}

__global__ __launch_bounds__(64) void res_c_kernel(
    const float* __restrict__ XC, float* __restrict__ out,
    const float* __restrict__ CW) {
  __shared__ float sm[4096];
  poly_scan(XC + (size_t)blockIdx.x * T_, out + (size_t)blockIdx.x * T_,
            CW + 64, sm);
}

// ---------------- launch ----------------
extern "C" void kernel_launch(void* const* d_in, const int* in_sizes, int n_in,
                              void* d_out, int out_size, void* d_ws, size_t ws_size,
                              hipStream_t stream) {
  const float* f0    = (const float*)d_in[0];
  const float* amps  = (const float*)d_in[1];
  const float* fmg   = (const float*)d_in[2];
  const float* cps   = (const float*)d_in[4];
  const float* nba   = (const float*)d_in[5];
  const float* nps   = (const float*)d_in[6];
  const float* npg   = (const float*)d_in[7];
  const float* fng   = (const float*)d_in[8];
  const float* bands = (const float*)d_in[9];
  const float* da  = (const float*)d_in[10];
  const float* fga = (const float*)d_in[11];
  const float* ra  = (const float*)d_in[12];
  const float* db  = (const float*)d_in[13];
  const float* fgb = (const float*)d_in[14];
  const float* rb  = (const float*)d_in[15];
  const float* dc  = (const float*)d_in[16];
  const float* fgc = (const float*)d_in[17];
  const float* rc  = (const float*)d_in[18];
  float* out = (float*)d_out;
  float* ws  = (float*)d_ws;

  // slots of 131072 floats (B*T):
  float* S0 = ws;              // pcp  -> later XA (x''_a)
  float* S1 = ws + 131072;     // bank_a -> later RA (res_a)
  float* S2 = ws + 262144;     // bank_b -> later RB (res_b)
  float* S3 = ws + 393216;     // XB (x''_b) -> later XC (x''_c)
  float* CW = ws + 524288;     // coefficients (96 floats)

  pcp_coef_kernel<<<3, 1024, 0, stream>>>(f0, S0, da, fga, ra, db, fgb, rb,
                                          dc, fgc, rc, CW);
  synth_kernel<<<512, 256, 0, stream>>>(amps, fmg, cps, nba, nps, npg, fng, bands,
                                        S0, S1, S2);
  // feedforward for banks: XA<-S0 (pcp dead), XB<-S3; reads banks S1,S2
  prep_ab_kernel<<<256, 256, 0, stream>>>(S1, S2, CW, S0, S3);
  // scans: RA->S1 (bank_a dead), RB->S2 (bank_b dead); reads XA=S0, XB=S3
  res_ab_kernel<<<4, 64, 0, stream>>>(S0, S3, S1, S2, CW);
  // feedforward for c: XC<-S3 (XB dead); reads RA=S1, RB=S2
  prep_c_kernel<<<128, 256, 0, stream>>>(S1, S2, CW, S3);
  res_c_kernel<<<2, 64, 0, stream>>>(S3, out, CW);
}